// Round 13
// baseline (286.561 us; speedup 1.0000x reference)
//
#include <hip/hip_runtime.h>
#include <hip/hip_bf16.h>

#define NEG_SLOPE 0.1f
#define EPB 4096        // edges per block for binning passes
#define BINSH 9         // 512 nodes per bin
#define DMAX 256        // degree clamp for sort (true max deg ~50 at E/N=16)

typedef __attribute__((ext_vector_type(8))) short bf16x8;
typedef __attribute__((ext_vector_type(4))) float f32x4;

__device__ __forceinline__ float bflo(unsigned u) { return __uint_as_float(u << 16); }
__device__ __forceinline__ float bfhi(unsigned u) { return __uint_as_float(u & 0xffff0000u); }
__device__ __forceinline__ unsigned short f2bf(float f) {
    __hip_bfloat16 h = __float2bfloat16(f);
    unsigned short r;
    __builtin_memcpy(&r, &h, 2);
    return r;
}

// ---------------- CSR build (binned) + weight prep fused ----------------
__global__ __launch_bounds__(256) void binhist_k(const int* __restrict__ dst,
                                                 int* __restrict__ bin_counts, int E,
                                                 const float* __restrict__ W1,
                                                 const float* __restrict__ W2,
                                                 const float* __restrict__ Wm,
                                                 unsigned short* __restrict__ Wt1,
                                                 unsigned short* __restrict__ Wt2,
                                                 unsigned short* __restrict__ Wtm) {
    __shared__ int cnt[256];
    int t = threadIdx.x;
    cnt[t] = 0;
    __syncthreads();
    int base = blockIdx.x * EPB;
    if (base + EPB <= E) {
        const int4* d4 = (const int4*)(dst + base);
        #pragma unroll
        for (int i = 0; i < 4; ++i) {
            int4 v = d4[i * 256 + t];
            atomicAdd(&cnt[v.x >> BINSH], 1);
            atomicAdd(&cnt[v.y >> BINSH], 1);
            atomicAdd(&cnt[v.z >> BINSH], 1);
            atomicAdd(&cnt[v.w >> BINSH], 1);
        }
    } else {
        for (int i = 0; i < 4; ++i) {
            int j0 = base + (i * 256 + t) * 4;
            #pragma unroll
            for (int c = 0; c < 4; ++c)
                if (j0 + c < E) atomicAdd(&cnt[dst[j0 + c] >> BINSH], 1);
        }
    }
    // fused weight prep: blocks 0..255 each convert 256 weight elems
    int id = blockIdx.x * 256 + t;
    if (id < 16384) {
        int k = id >> 7, c = id & 127;
        Wt1[c * 128 + k] = f2bf(W1[id]);
    } else if (id < 32768) {
        int e = id - 16384; int k = e >> 7, c = e & 127;
        Wt2[c * 128 + k] = f2bf(W2[e]);
    } else if (id < 65536) {
        int e = id - 32768;            // Wm is [256][128]
        int k = e >> 7, c = e & 127;
        Wtm[c * 256 + k] = f2bf(Wm[e]);
    }
    __syncthreads();
    if (cnt[t]) atomicAdd(&bin_counts[t], cnt[t]);
}

__global__ __launch_bounds__(256) void scan256_k(const int* __restrict__ bin_counts,
                                                 int* __restrict__ binoffs,
                                                 int* __restrict__ gcur, int nbins) {
    __shared__ int sbuf[256];
    int t = threadIdx.x;
    int c = (t < nbins) ? bin_counts[t] : 0;
    sbuf[t] = c;
    __syncthreads();
    for (int off = 1; off < 256; off <<= 1) {
        int u = (t >= off) ? sbuf[t - off] : 0;
        __syncthreads();
        sbuf[t] += u;
        __syncthreads();
    }
    int ex = sbuf[t] - c;
    binoffs[t] = ex;
    if (t == 255) binoffs[256] = ex + c;
    gcur[t] = ex;
}

// tmp entry packed: {src | (dst&511)<<17, w}  (needs N < 131072)
__global__ __launch_bounds__(256) void binify_k(const int* __restrict__ src,
                                                const int* __restrict__ dst,
                                                const float* __restrict__ w,
                                                int* __restrict__ gcur,
                                                int2* __restrict__ tmp, int E) {
    __shared__ int cnt[256];
    __shared__ int basearr[256];
    int t = threadIdx.x;
    cnt[t] = 0;
    __syncthreads();
    int base = blockIdx.x * EPB;
    int es[16], ed[16], ew[16];
    bool va[16];
    if (base + EPB <= E) {
        const int4* s4 = (const int4*)(src + base);
        const int4* d4 = (const int4*)(dst + base);
        const int4* w4 = (const int4*)(w + base);
        #pragma unroll
        for (int i = 0; i < 4; ++i) {
            int slot = i * 256 + t;
            int4 sv = s4[slot]; int4 dv = d4[slot]; int4 wv = w4[slot];
            es[i*4+0]=sv.x; es[i*4+1]=sv.y; es[i*4+2]=sv.z; es[i*4+3]=sv.w;
            ed[i*4+0]=dv.x; ed[i*4+1]=dv.y; ed[i*4+2]=dv.z; ed[i*4+3]=dv.w;
            ew[i*4+0]=wv.x; ew[i*4+1]=wv.y; ew[i*4+2]=wv.z; ew[i*4+3]=wv.w;
            va[i*4+0]=va[i*4+1]=va[i*4+2]=va[i*4+3]=true;
        }
    } else {
        #pragma unroll
        for (int i = 0; i < 4; ++i) {
            #pragma unroll
            for (int c = 0; c < 4; ++c) {
                int j = base + (i * 256 + t) * 4 + c;
                bool v = j < E;
                va[i*4+c] = v;
                es[i*4+c] = v ? src[j] : 0;
                ed[i*4+c] = v ? dst[j] : 0;
                ew[i*4+c] = v ? __float_as_int(w[j]) : 0;
            }
        }
    }
    #pragma unroll
    for (int i = 0; i < 16; ++i)
        if (va[i]) atomicAdd(&cnt[ed[i] >> BINSH], 1);
    __syncthreads();
    int c = cnt[t];
    basearr[t] = c ? atomicAdd(&gcur[t], c) : 0;
    __syncthreads();
    cnt[t] = 0;
    __syncthreads();
    #pragma unroll
    for (int i = 0; i < 16; ++i) {
        if (va[i]) {
            int b = ed[i] >> BINSH;
            int pos = atomicAdd(&cnt[b], 1);
            tmp[basearr[b] + pos] = make_int2(es[i] | ((ed[i] & 511) << 17), ew[i]);
        }
    }
}

// per-bin finalize + fused degree histogram
__global__ __launch_bounds__(256) void binfin_k(const int2* __restrict__ tmp,
                                                const int* __restrict__ binoffs,
                                                int* __restrict__ offs,
                                                int2* __restrict__ snw,
                                                int* __restrict__ dhist, int N, int E) {
    __shared__ int ncnt[512];
    __shared__ int noff[512];
    __shared__ int sbuf[256];
    __shared__ int dh[DMAX];
    int b = blockIdx.x, t = threadIdx.x;
    int lo = b << BINSH;
    int hi = min(lo + 512, N);
    int ebeg = binoffs[b], eend = binoffs[b + 1];
    ncnt[t] = 0; ncnt[t + 256] = 0; dh[t] = 0;
    __syncthreads();
    for (int j = ebeg + t; j < eend; j += 256)
        atomicAdd(&ncnt[(unsigned)tmp[j].x >> 17], 1);
    __syncthreads();
    int a0 = ncnt[2 * t], a1 = ncnt[2 * t + 1];
    sbuf[t] = a0 + a1;
    __syncthreads();
    for (int off = 1; off < 256; off <<= 1) {
        int u = (t >= off) ? sbuf[t - off] : 0;
        __syncthreads();
        sbuf[t] += u;
        __syncthreads();
    }
    int ex = sbuf[t] - (a0 + a1);
    noff[2 * t] = ex;
    noff[2 * t + 1] = ex + a0;
    if (lo + 2 * t < hi) {
        offs[lo + 2 * t] = ebeg + ex;
        atomicAdd(&dh[min(a0, DMAX - 1)], 1);
    }
    if (lo + 2 * t + 1 < hi) {
        offs[lo + 2 * t + 1] = ebeg + ex + a0;
        atomicAdd(&dh[min(a1, DMAX - 1)], 1);
    }
    if (b == 0 && t == 0) offs[N] = E;
    ncnt[t] = 0; ncnt[t + 256] = 0;
    __syncthreads();
    if (dh[t]) atomicAdd(&dhist[t], dh[t]);
    for (int j = ebeg + t; j < eend; j += 256) {
        int2 e = tmp[j];
        int idx = (unsigned)e.x >> 17;
        int pos = atomicAdd(&ncnt[idx], 1);
        snw[ebeg + noff[idx] + pos] = make_int2(e.x & 0x1ffff, e.y);
    }
}

// ---------------- degree-sorted node permutation ----------------
__global__ __launch_bounds__(256) void degscan_k(const int* __restrict__ dhist,
                                                 int* __restrict__ dcur) {
    __shared__ int buf[DMAX];
    int t = threadIdx.x;
    int v = dhist[t];
    buf[t] = v;
    __syncthreads();
    for (int off = 1; off < DMAX; off <<= 1) {
        int u = (t >= off) ? buf[t - off] : 0;
        __syncthreads();
        buf[t] += u;
        __syncthreads();
    }
    dcur[t] = buf[t] - v;   // exclusive
}

__global__ __launch_bounds__(256) void degscat_k(const int* __restrict__ offs,
                                                 int* __restrict__ dcur,
                                                 int* __restrict__ perm, int N) {
    __shared__ int cnt[DMAX];
    __shared__ int basea[DMAX];
    int t = threadIdx.x;
    cnt[t] = 0;
    __syncthreads();
    int n = blockIdx.x * 256 + t;
    int d = -1;
    if (n < N) {
        d = min(offs[n + 1] - offs[n], DMAX - 1);
        atomicAdd(&cnt[d], 1);
    }
    __syncthreads();
    int c = cnt[t];
    basea[t] = c ? atomicAdd(&dcur[t], c) : 0;
    __syncthreads();
    cnt[t] = 0;
    __syncthreads();
    if (n < N) {
        int pos = atomicAdd(&cnt[d], 1);
        perm[basea[d] + pos] = n;
    }
}

// ---------------- MFMA GEMM (LDS-staged; bf16 paths use global_load_lds) ----------------
// T21 pattern: linear LDS dest (wave-uniform base + lane*16) + inverse-swizzled
// per-lane GLOBAL source (chunk (lane&15)^(row&7)) + swizzled read (unchanged).
template<int K, bool A_F32, bool BIAS, bool OUT_BF16>
__global__ __launch_bounds__(256) void gemm_mfma(const void* __restrict__ A0v,
                                                 const void* __restrict__ A1v,
                                                 const unsigned short* __restrict__ Wt,
                                                 const float* __restrict__ bias,
                                                 void* __restrict__ Cv, int M) {
    __shared__ __align__(16) unsigned short At[128 * 128];
    __shared__ __align__(16) unsigned short Bt[128 * 128];
    const int t = threadIdx.x;
    const int lane = t & 63;
    const int wv = t >> 6;
    const int m0 = blockIdx.x * 128;
    const int l15 = lane & 15;
    const int l4 = lane >> 4;

    f32x4 acc[2][8];
    #pragma unroll
    for (int r = 0; r < 2; ++r)
        #pragma unroll
        for (int c = 0; c < 8; ++c) acc[r][c] = (f32x4){0.f, 0.f, 0.f, 0.f};

    const int srow = t >> 4;
    const int scol = (t & 15) * 8;

    for (int k0 = 0; k0 < K; k0 += 128) {
        const int chunk = k0 >> 7;
        // ---- stage A ----
        if (A_F32) {
            #pragma unroll
            for (int p = 0; p < 8; ++p) {
                int row = p * 16 + srow;
                int gm = p * 16 + srow + m0;
                uint4 pk = make_uint4(0, 0, 0, 0);
                const float* Ap = (const float*)A0v;
                float4 f0 = make_float4(0.f,0.f,0.f,0.f), f1 = f0;
                if (gm < M) {
                    f0 = *(const float4*)(Ap + (size_t)gm * 128 + scol);
                    f1 = *(const float4*)(Ap + (size_t)gm * 128 + scol + 4);
                }
                pk.x = f2bf(f0.x) | ((unsigned)f2bf(f0.y) << 16);
                pk.y = f2bf(f0.z) | ((unsigned)f2bf(f0.w) << 16);
                pk.z = f2bf(f1.x) | ((unsigned)f2bf(f1.y) << 16);
                pk.w = f2bf(f1.z) | ((unsigned)f2bf(f1.w) << 16);
                int byte = (row * 256 + scol * 2) ^ ((row & 7) << 4);
                *(uint4*)((char*)At + byte) = pk;
            }
        } else {
            const unsigned short* Ap = (const unsigned short*)(chunk ? A1v : A0v);
            #pragma unroll
            for (int p = 0; p < 8; ++p) {
                int rowbase = p * 16 + wv * 4;            // wave-uniform
                int row = rowbase + l4 / 1;               // + (lane>>4)
                row = rowbase + (lane >> 4);
                int gm = min(m0 + row, M - 1);            // clamp; masked at store
                int ck = (lane & 15) ^ (row & 7);         // inverse swizzle on source
                const unsigned short* gsrc = Ap + (size_t)gm * 128 + ck * 8;
                __builtin_amdgcn_global_load_lds(
                    (const __attribute__((address_space(1))) void*)gsrc,
                    (__attribute__((address_space(3))) void*)((char*)At + rowbase * 256),
                    16, 0, 0);
            }
        }
        // ---- stage B (always bf16, global_load_lds) ----
        #pragma unroll
        for (int p = 0; p < 8; ++p) {
            int rowbase = p * 16 + wv * 4;
            int row = rowbase + (lane >> 4);
            int ck = (lane & 15) ^ (row & 7);
            const unsigned short* gsrc = Wt + (size_t)row * K + k0 + ck * 8;
            __builtin_amdgcn_global_load_lds(
                (const __attribute__((address_space(1))) void*)gsrc,
                (__attribute__((address_space(3))) void*)((char*)Bt + rowbase * 256),
                16, 0, 0);
        }
        __syncthreads();
        // ---- MFMA over this K-chunk (reads identical to Round-10) ----
        #pragma unroll
        for (int ks = 0; ks < 4; ++ks) {
            int kb = ks * 32 + l4 * 8;
            bf16x8 af[2], bfv[8];
            #pragma unroll
            for (int r = 0; r < 2; ++r) {
                int row = wv * 32 + r * 16 + l15;
                int byte = (row * 256 + kb * 2) ^ ((row & 7) << 4);
                af[r] = *(const bf16x8*)((char*)At + byte);
            }
            #pragma unroll
            for (int c = 0; c < 8; ++c) {
                int col = c * 16 + l15;
                int byte = (col * 256 + kb * 2) ^ ((col & 7) << 4);
                bfv[c] = *(const bf16x8*)((char*)Bt + byte);
            }
            #pragma unroll
            for (int r = 0; r < 2; ++r)
                #pragma unroll
                for (int c = 0; c < 8; ++c)
                    acc[r][c] = __builtin_amdgcn_mfma_f32_16x16x32_bf16(af[r], bfv[c], acc[r][c], 0, 0, 0);
        }
        __syncthreads();
    }
    float bb[8];
    if (BIAS) {
        #pragma unroll
        for (int c = 0; c < 8; ++c) bb[c] = bias[c * 16 + l15];
    }
    #pragma unroll
    for (int r = 0; r < 2; ++r) {
        #pragma unroll
        for (int q = 0; q < 4; ++q) {
            int row = m0 + wv * 32 + r * 16 + l4 * 4 + q;
            if (row < M) {
                #pragma unroll
                for (int c = 0; c < 8; ++c) {
                    int col = c * 16 + l15;
                    float v = acc[r][c][q];
                    if (BIAS) v += bb[c];
                    if (OUT_BF16) ((unsigned short*)Cv)[(size_t)row * 128 + col] = f2bf(v);
                    else          ((float*)Cv)[(size_t)row * 128 + col] = v;
                }
            }
        }
    }
}

// ---------------- aggregation v5: single-phase streaming ----------------
__global__ __launch_bounds__(256) void agg_k(const __hip_bfloat16* __restrict__ ftb,
                                             const int2* __restrict__ snw,
                                             const int* __restrict__ offs,
                                             const int* __restrict__ perm,
                                             const float* __restrict__ AL,
                                             const float* __restrict__ AR,
                                             unsigned short* __restrict__ out, int n) {
    int tid = threadIdx.x;
    int gl = tid & 15;
    int hd = gl >> 1;
    unsigned gl16 = (unsigned)(gl * 16);
    int idx = blockIdx.x * 16 + (tid >> 4);
    bool valid = idx < n;
    int node = valid ? perm[idx] : 0;
    int beg = 0, deg = 0;
    if (valid) { beg = offs[node]; deg = offs[node + 1] - beg; }
    const char* fb = (const char*)ftb;

    float alf[8], arf[8];
    {
        const float* ap = AL + hd * 16 + (gl & 1) * 8;
        const float* rp = AR + hd * 16 + (gl & 1) * 8;
        #pragma unroll
        for (int d = 0; d < 8; ++d) { alf[d] = ap[d]; arf[d] = rp[d]; }
    }

    float er_h;
    {
        uint4 mu = *(const uint4*)(fb + ((unsigned)node << 8) + gl16);
        float ep = arf[0] * bflo(mu.x) + arf[1] * bfhi(mu.x)
                 + arf[2] * bflo(mu.y) + arf[3] * bfhi(mu.y)
                 + arf[4] * bflo(mu.z) + arf[5] * bfhi(mu.z)
                 + arf[6] * bflo(mu.w) + arf[7] * bfhi(mu.w);
        er_h = ep + __shfl_xor(ep, 1);
    }

    float acc[8];
    #pragma unroll
    for (int k = 0; k < 8; ++k) acc[k] = 0.f;
    float s = 0.f;

    for (int j0 = 0; j0 < deg; j0 += 8) {
        uint4 rv[8];
        float wv8[8];
        #pragma unroll
        for (int q = 0; q < 8; ++q) {
            int j = j0 + q;
            bool act = j < deg;
            int2 p2 = snw[act ? beg + j : 0];
            wv8[q] = act ? __int_as_float(p2.y) : 0.f;
            unsigned ad = act ? (((unsigned)p2.x << 8) + gl16) : gl16;
            rv[q] = *(const uint4*)(fb + ad);
        }
        #pragma unroll
        for (int q = 0; q < 8; ++q) {
            float ep = alf[0] * bflo(rv[q].x) + alf[1] * bfhi(rv[q].x)
                     + alf[2] * bflo(rv[q].y) + alf[3] * bfhi(rv[q].y)
                     + alf[4] * bflo(rv[q].z) + alf[5] * bfhi(rv[q].z)
                     + alf[6] * bflo(rv[q].w) + alf[7] * bfhi(rv[q].w);
            float el_h = ep + __shfl_xor(ep, 1);
            float tt = el_h + er_h;
            tt = tt > 0.f ? tt : NEG_SLOPE * tt;
            float p = __expf(tt * wv8[q]);
            p = (j0 + q < deg) ? p : 0.f;
            s += p;
            acc[0] += p * bflo(rv[q].x); acc[1] += p * bfhi(rv[q].x);
            acc[2] += p * bflo(rv[q].y); acc[3] += p * bfhi(rv[q].y);
            acc[4] += p * bflo(rv[q].z); acc[5] += p * bfhi(rv[q].z);
            acc[6] += p * bflo(rv[q].w); acc[7] += p * bfhi(rv[q].w);
        }
    }

    if (valid) {
        float sinv = s > 0.f ? 1.f / s : 0.f;
        float o[8];
        #pragma unroll
        for (int k = 0; k < 8; ++k) o[k] = fmaxf(acc[k] * sinv, 0.f);
        uint4 pk;
        pk.x = f2bf(o[0]) | ((unsigned)f2bf(o[1]) << 16);
        pk.y = f2bf(o[2]) | ((unsigned)f2bf(o[3]) << 16);
        pk.z = f2bf(o[4]) | ((unsigned)f2bf(o[5]) << 16);
        pk.w = f2bf(o[6]) | ((unsigned)f2bf(o[7]) << 16);
        *(uint4*)((char*)out + ((size_t)node << 8) + gl16) = pk;
    }
}

extern "C" void kernel_launch(void* const* d_in, const int* in_sizes, int n_in,
                              void* d_out, int out_size, void* d_ws, size_t ws_size,
                              hipStream_t stream) {
    const float* features = (const float*)d_in[0];
    const int*   src      = (const int*)d_in[1];
    const int*   dst      = (const int*)d_in[2];
    const float* w        = (const float*)d_in[3];
    const float* W1       = (const float*)d_in[4];
    const float* al1      = (const float*)d_in[5];
    const float* ar1      = (const float*)d_in[6];
    const float* W2       = (const float*)d_in[7];
    const float* al2      = (const float*)d_in[8];
    const float* ar2      = (const float*)d_in[9];
    const float* Wm       = (const float*)d_in[10];
    const float* bm       = (const float*)d_in[11];
    float* out = (float*)d_out;

    const int N = in_sizes[0] / 128;   // 100000 < 2^17 (packing assumption)
    const int E = in_sizes[1];

    char* ws = (char*)d_ws;
    unsigned short* ftb = (unsigned short*)ws;            ws += (size_t)N * 128 * 2;
    unsigned short* x1b = (unsigned short*)ws;            ws += (size_t)N * 128 * 2;
    unsigned short* x2b = (unsigned short*)ws;            ws += (size_t)N * 128 * 2;
    unsigned short* Wt1 = (unsigned short*)ws;            ws += (size_t)128 * 128 * 2;
    unsigned short* Wt2 = (unsigned short*)ws;            ws += (size_t)128 * 128 * 2;
    unsigned short* Wtm = (unsigned short*)ws;            ws += (size_t)128 * 256 * 2;
    int* offs      = (int*)ws;                            ws += (size_t)(N + 4) * 4;
    int* bin_counts= (int*)ws;                            ws += 256 * 4;
    int* binoffs   = (int*)ws;                            ws += 260 * 4;
    int* gcur      = (int*)ws;                            ws += 256 * 4;
    int* dhist     = (int*)ws;                            ws += DMAX * 4;
    int* dcur      = (int*)ws;                            ws += DMAX * 4;
    int* perm      = (int*)ws;                            ws += (size_t)N * 4;
    int2* snw      = (int2*)ws;                           ws += (size_t)E * 8;
    int2* tmp      = (int2*)ws;                           ws += (size_t)E * 8;

    hipMemsetAsync(bin_counts, 0, 256 * sizeof(int), stream);
    hipMemsetAsync(dhist, 0, DMAX * sizeof(int), stream);

    const int nbins = (N + 511) >> BINSH;
    const int nblk_e = (E + EPB - 1) / EPB;
    const int nblk_n = (N + 255) / 256;

    binhist_k<<<nblk_e, 256, 0, stream>>>(dst, bin_counts, E, W1, W2, Wm, Wt1, Wt2, Wtm);
    scan256_k<<<1, 256, 0, stream>>>(bin_counts, binoffs, gcur, nbins);
    binify_k<<<nblk_e, 256, 0, stream>>>(src, dst, w, gcur, tmp, E);
    binfin_k<<<nbins, 256, 0, stream>>>(tmp, binoffs, offs, snw, dhist, N, E);
    degscan_k<<<1, 256, 0, stream>>>(dhist, dcur);
    degscat_k<<<nblk_n, 256, 0, stream>>>(offs, dcur, perm, N);

    int gemm_grid = (N + 127) / 128;
    int agg_grid = (N + 15) / 16;

    // ---- layer 1 ----
    gemm_mfma<128, true, false, true><<<gemm_grid, 256, 0, stream>>>(features, nullptr, Wt1, nullptr, ftb, N);
    agg_k<<<agg_grid, 256, 0, stream>>>((const __hip_bfloat16*)ftb, snw, offs, perm, al1, ar1, x1b, N);

    // ---- layer 2 ----
    gemm_mfma<128, false, false, true><<<gemm_grid, 256, 0, stream>>>(x1b, nullptr, Wt2, nullptr, ftb, N);
    agg_k<<<agg_grid, 256, 0, stream>>>((const __hip_bfloat16*)ftb, snw, offs, perm, al2, ar2, x2b, N);

    // ---- final: [x1|x2] @ Wm + bm (f32 out) ----
    gemm_mfma<256, false, true, false><<<gemm_grid, 256, 0, stream>>>(x1b, x2b, Wtm, bm, out, N);
}

// Round 14
// 281.762 us; speedup vs baseline: 1.0170x; 1.0170x over previous
//
#include <hip/hip_runtime.h>
#include <hip/hip_bf16.h>

#define NEG_SLOPE 0.1f
#define EPB 4096        // edges per block for binning passes
#define BINSH 9         // 512 nodes per bin
#define DMAX 256        // degree clamp for sort (true max deg ~50 at E/N=16)

typedef __attribute__((ext_vector_type(8))) short bf16x8;
typedef __attribute__((ext_vector_type(4))) float f32x4;

__device__ __forceinline__ float bflo(unsigned u) { return __uint_as_float(u << 16); }
__device__ __forceinline__ float bfhi(unsigned u) { return __uint_as_float(u & 0xffff0000u); }
__device__ __forceinline__ unsigned short f2bf(float f) {
    __hip_bfloat16 h = __float2bfloat16(f);
    unsigned short r;
    __builtin_memcpy(&r, &h, 2);
    return r;
}

// ---------------- CSR build (binned) + weight prep fused ----------------
__global__ __launch_bounds__(256) void binhist_k(const int* __restrict__ dst,
                                                 int* __restrict__ bin_counts, int E,
                                                 const float* __restrict__ W1,
                                                 const float* __restrict__ W2,
                                                 const float* __restrict__ Wm,
                                                 unsigned short* __restrict__ Wt1,
                                                 unsigned short* __restrict__ Wt2,
                                                 unsigned short* __restrict__ Wtm) {
    __shared__ int cnt[256];
    int t = threadIdx.x;
    cnt[t] = 0;
    __syncthreads();
    int base = blockIdx.x * EPB;
    if (base + EPB <= E) {
        const int4* d4 = (const int4*)(dst + base);
        #pragma unroll
        for (int i = 0; i < 4; ++i) {
            int4 v = d4[i * 256 + t];
            atomicAdd(&cnt[v.x >> BINSH], 1);
            atomicAdd(&cnt[v.y >> BINSH], 1);
            atomicAdd(&cnt[v.z >> BINSH], 1);
            atomicAdd(&cnt[v.w >> BINSH], 1);
        }
    } else {
        for (int i = 0; i < 4; ++i) {
            int j0 = base + (i * 256 + t) * 4;
            #pragma unroll
            for (int c = 0; c < 4; ++c)
                if (j0 + c < E) atomicAdd(&cnt[dst[j0 + c] >> BINSH], 1);
        }
    }
    // fused weight prep: blocks 0..255 each convert 256 weight elems
    int id = blockIdx.x * 256 + t;
    if (id < 16384) {
        int k = id >> 7, c = id & 127;
        Wt1[c * 128 + k] = f2bf(W1[id]);
    } else if (id < 32768) {
        int e = id - 16384; int k = e >> 7, c = e & 127;
        Wt2[c * 128 + k] = f2bf(W2[e]);
    } else if (id < 65536) {
        int e = id - 32768;            // Wm is [256][128]
        int k = e >> 7, c = e & 127;
        Wtm[c * 256 + k] = f2bf(Wm[e]);
    }
    __syncthreads();
    if (cnt[t]) atomicAdd(&bin_counts[t], cnt[t]);
}

__global__ __launch_bounds__(256) void scan256_k(const int* __restrict__ bin_counts,
                                                 int* __restrict__ binoffs,
                                                 int* __restrict__ gcur, int nbins) {
    __shared__ int sbuf[256];
    int t = threadIdx.x;
    int c = (t < nbins) ? bin_counts[t] : 0;
    sbuf[t] = c;
    __syncthreads();
    for (int off = 1; off < 256; off <<= 1) {
        int u = (t >= off) ? sbuf[t - off] : 0;
        __syncthreads();
        sbuf[t] += u;
        __syncthreads();
    }
    int ex = sbuf[t] - c;
    binoffs[t] = ex;
    if (t == 255) binoffs[256] = ex + c;
    gcur[t] = ex;
}

// tmp entry packed: {src | (dst&511)<<17, w}  (needs N < 131072)
__global__ __launch_bounds__(256) void binify_k(const int* __restrict__ src,
                                                const int* __restrict__ dst,
                                                const float* __restrict__ w,
                                                int* __restrict__ gcur,
                                                int2* __restrict__ tmp, int E) {
    __shared__ int cnt[256];
    __shared__ int basearr[256];
    int t = threadIdx.x;
    cnt[t] = 0;
    __syncthreads();
    int base = blockIdx.x * EPB;
    int es[16], ed[16], ew[16];
    bool va[16];
    if (base + EPB <= E) {
        const int4* s4 = (const int4*)(src + base);
        const int4* d4 = (const int4*)(dst + base);
        const int4* w4 = (const int4*)(w + base);
        #pragma unroll
        for (int i = 0; i < 4; ++i) {
            int slot = i * 256 + t;
            int4 sv = s4[slot]; int4 dv = d4[slot]; int4 wv = w4[slot];
            es[i*4+0]=sv.x; es[i*4+1]=sv.y; es[i*4+2]=sv.z; es[i*4+3]=sv.w;
            ed[i*4+0]=dv.x; ed[i*4+1]=dv.y; ed[i*4+2]=dv.z; ed[i*4+3]=dv.w;
            ew[i*4+0]=wv.x; ew[i*4+1]=wv.y; ew[i*4+2]=wv.z; ew[i*4+3]=wv.w;
            va[i*4+0]=va[i*4+1]=va[i*4+2]=va[i*4+3]=true;
        }
    } else {
        #pragma unroll
        for (int i = 0; i < 4; ++i) {
            #pragma unroll
            for (int c = 0; c < 4; ++c) {
                int j = base + (i * 256 + t) * 4 + c;
                bool v = j < E;
                va[i*4+c] = v;
                es[i*4+c] = v ? src[j] : 0;
                ed[i*4+c] = v ? dst[j] : 0;
                ew[i*4+c] = v ? __float_as_int(w[j]) : 0;
            }
        }
    }
    #pragma unroll
    for (int i = 0; i < 16; ++i)
        if (va[i]) atomicAdd(&cnt[ed[i] >> BINSH], 1);
    __syncthreads();
    int c = cnt[t];
    basearr[t] = c ? atomicAdd(&gcur[t], c) : 0;
    __syncthreads();
    cnt[t] = 0;
    __syncthreads();
    #pragma unroll
    for (int i = 0; i < 16; ++i) {
        if (va[i]) {
            int b = ed[i] >> BINSH;
            int pos = atomicAdd(&cnt[b], 1);
            tmp[basearr[b] + pos] = make_int2(es[i] | ((ed[i] & 511) << 17), ew[i]);
        }
    }
}

// per-bin finalize + fused degree histogram
__global__ __launch_bounds__(256) void binfin_k(const int2* __restrict__ tmp,
                                                const int* __restrict__ binoffs,
                                                int* __restrict__ offs,
                                                int2* __restrict__ snw,
                                                int* __restrict__ dhist, int N, int E) {
    __shared__ int ncnt[512];
    __shared__ int noff[512];
    __shared__ int sbuf[256];
    __shared__ int dh[DMAX];
    int b = blockIdx.x, t = threadIdx.x;
    int lo = b << BINSH;
    int hi = min(lo + 512, N);
    int ebeg = binoffs[b], eend = binoffs[b + 1];
    ncnt[t] = 0; ncnt[t + 256] = 0; dh[t] = 0;
    __syncthreads();
    for (int j = ebeg + t; j < eend; j += 256)
        atomicAdd(&ncnt[(unsigned)tmp[j].x >> 17], 1);
    __syncthreads();
    int a0 = ncnt[2 * t], a1 = ncnt[2 * t + 1];
    sbuf[t] = a0 + a1;
    __syncthreads();
    for (int off = 1; off < 256; off <<= 1) {
        int u = (t >= off) ? sbuf[t - off] : 0;
        __syncthreads();
        sbuf[t] += u;
        __syncthreads();
    }
    int ex = sbuf[t] - (a0 + a1);
    noff[2 * t] = ex;
    noff[2 * t + 1] = ex + a0;
    if (lo + 2 * t < hi) {
        offs[lo + 2 * t] = ebeg + ex;
        atomicAdd(&dh[min(a0, DMAX - 1)], 1);
    }
    if (lo + 2 * t + 1 < hi) {
        offs[lo + 2 * t + 1] = ebeg + ex + a0;
        atomicAdd(&dh[min(a1, DMAX - 1)], 1);
    }
    if (b == 0 && t == 0) offs[N] = E;
    ncnt[t] = 0; ncnt[t + 256] = 0;
    __syncthreads();
    if (dh[t]) atomicAdd(&dhist[t], dh[t]);
    for (int j = ebeg + t; j < eend; j += 256) {
        int2 e = tmp[j];
        int idx = (unsigned)e.x >> 17;
        int pos = atomicAdd(&ncnt[idx], 1);
        snw[ebeg + noff[idx] + pos] = make_int2(e.x & 0x1ffff, e.y);
    }
}

// ---------------- degree-sorted node permutation ----------------
__global__ __launch_bounds__(256) void degscan_k(const int* __restrict__ dhist,
                                                 int* __restrict__ dcur) {
    __shared__ int buf[DMAX];
    int t = threadIdx.x;
    int v = dhist[t];
    buf[t] = v;
    __syncthreads();
    for (int off = 1; off < DMAX; off <<= 1) {
        int u = (t >= off) ? buf[t - off] : 0;
        __syncthreads();
        buf[t] += u;
        __syncthreads();
    }
    dcur[t] = buf[t] - v;   // exclusive
}

__global__ __launch_bounds__(256) void degscat_k(const int* __restrict__ offs,
                                                 int* __restrict__ dcur,
                                                 int* __restrict__ perm, int N) {
    __shared__ int cnt[DMAX];
    __shared__ int basea[DMAX];
    int t = threadIdx.x;
    cnt[t] = 0;
    __syncthreads();
    int n = blockIdx.x * 256 + t;
    int d = -1;
    if (n < N) {
        d = min(offs[n + 1] - offs[n], DMAX - 1);
        atomicAdd(&cnt[d], 1);
    }
    __syncthreads();
    int c = cnt[t];
    basea[t] = c ? atomicAdd(&dcur[t], c) : 0;
    __syncthreads();
    cnt[t] = 0;
    __syncthreads();
    if (n < N) {
        int pos = atomicAdd(&cnt[d], 1);
        perm[basea[d] + pos] = n;
    }
}

// ---------------- MFMA GEMM (LDS-staged, XOR-swizzled: known-good 282.7us config) ----------------
template<int K, bool A_F32, bool BIAS, bool OUT_BF16>
__global__ __launch_bounds__(256) void gemm_mfma(const void* __restrict__ A0v,
                                                 const void* __restrict__ A1v,
                                                 const unsigned short* __restrict__ Wt,
                                                 const float* __restrict__ bias,
                                                 void* __restrict__ Cv, int M) {
    __shared__ __align__(16) unsigned short At[128 * 128];
    __shared__ __align__(16) unsigned short Bt[128 * 128];
    const int t = threadIdx.x;
    const int lane = t & 63;
    const int wv = t >> 6;
    const int m0 = blockIdx.x * 128;
    const int l15 = lane & 15;
    const int l4 = lane >> 4;

    f32x4 acc[2][8];
    #pragma unroll
    for (int r = 0; r < 2; ++r)
        #pragma unroll
        for (int c = 0; c < 8; ++c) acc[r][c] = (f32x4){0.f, 0.f, 0.f, 0.f};

    const int srow = t >> 4;
    const int scol = (t & 15) * 8;

    for (int k0 = 0; k0 < K; k0 += 128) {
        const int chunk = k0 >> 7;
        #pragma unroll
        for (int p = 0; p < 8; ++p) {
            int row = p * 16 + srow;
            int gm = m0 + row;
            uint4 pk = make_uint4(0, 0, 0, 0);
            if (A_F32) {
                const float* Ap = (const float*)(chunk ? A1v : A0v);
                float4 f0 = make_float4(0.f,0.f,0.f,0.f), f1 = f0;
                if (gm < M) {
                    f0 = *(const float4*)(Ap + (size_t)gm * 128 + scol);
                    f1 = *(const float4*)(Ap + (size_t)gm * 128 + scol + 4);
                }
                pk.x = f2bf(f0.x) | ((unsigned)f2bf(f0.y) << 16);
                pk.y = f2bf(f0.z) | ((unsigned)f2bf(f0.w) << 16);
                pk.z = f2bf(f1.x) | ((unsigned)f2bf(f1.y) << 16);
                pk.w = f2bf(f1.z) | ((unsigned)f2bf(f1.w) << 16);
            } else {
                const unsigned short* Ap = (const unsigned short*)(chunk ? A1v : A0v);
                if (gm < M) pk = *(const uint4*)(Ap + (size_t)gm * 128 + scol);
            }
            int byte = (row * 256 + scol * 2) ^ ((row & 7) << 4);
            *(uint4*)((char*)At + byte) = pk;
        }
        #pragma unroll
        for (int p = 0; p < 8; ++p) {
            int row = p * 16 + srow;
            uint4 pk = *(const uint4*)(Wt + (size_t)row * K + k0 + scol);
            int byte = (row * 256 + scol * 2) ^ ((row & 7) << 4);
            *(uint4*)((char*)Bt + byte) = pk;
        }
        __syncthreads();
        #pragma unroll
        for (int ks = 0; ks < 4; ++ks) {
            int kb = ks * 32 + l4 * 8;
            bf16x8 af[2], bfv[8];
            #pragma unroll
            for (int r = 0; r < 2; ++r) {
                int row = wv * 32 + r * 16 + l15;
                int byte = (row * 256 + kb * 2) ^ ((row & 7) << 4);
                af[r] = *(const bf16x8*)((char*)At + byte);
            }
            #pragma unroll
            for (int c = 0; c < 8; ++c) {
                int col = c * 16 + l15;
                int byte = (col * 256 + kb * 2) ^ ((col & 7) << 4);
                bfv[c] = *(const bf16x8*)((char*)Bt + byte);
            }
            #pragma unroll
            for (int r = 0; r < 2; ++r)
                #pragma unroll
                for (int c = 0; c < 8; ++c)
                    acc[r][c] = __builtin_amdgcn_mfma_f32_16x16x32_bf16(af[r], bfv[c], acc[r][c], 0, 0, 0);
        }
        __syncthreads();
    }
    float bb[8];
    if (BIAS) {
        #pragma unroll
        for (int c = 0; c < 8; ++c) bb[c] = bias[c * 16 + l15];
    }
    #pragma unroll
    for (int r = 0; r < 2; ++r) {
        #pragma unroll
        for (int q = 0; q < 4; ++q) {
            int row = m0 + wv * 32 + r * 16 + l4 * 4 + q;
            if (row < M) {
                #pragma unroll
                for (int c = 0; c < 8; ++c) {
                    int col = c * 16 + l15;
                    float v = acc[r][c][q];
                    if (BIAS) v += bb[c];
                    if (OUT_BF16) ((unsigned short*)Cv)[(size_t)row * 128 + col] = f2bf(v);
                    else          ((float*)Cv)[(size_t)row * 128 + col] = v;
                }
            }
        }
    }
}

// ---------------- aggregation v5: single-phase streaming ----------------
__global__ __launch_bounds__(256) void agg_k(const __hip_bfloat16* __restrict__ ftb,
                                             const int2* __restrict__ snw,
                                             const int* __restrict__ offs,
                                             const int* __restrict__ perm,
                                             const float* __restrict__ AL,
                                             const float* __restrict__ AR,
                                             unsigned short* __restrict__ out, int n) {
    int tid = threadIdx.x;
    int gl = tid & 15;
    int hd = gl >> 1;
    unsigned gl16 = (unsigned)(gl * 16);
    int idx = blockIdx.x * 16 + (tid >> 4);
    bool valid = idx < n;
    int node = valid ? perm[idx] : 0;
    int beg = 0, deg = 0;
    if (valid) { beg = offs[node]; deg = offs[node + 1] - beg; }
    const char* fb = (const char*)ftb;

    float alf[8], arf[8];
    {
        const float* ap = AL + hd * 16 + (gl & 1) * 8;
        const float* rp = AR + hd * 16 + (gl & 1) * 8;
        #pragma unroll
        for (int d = 0; d < 8; ++d) { alf[d] = ap[d]; arf[d] = rp[d]; }
    }

    float er_h;
    {
        uint4 mu = *(const uint4*)(fb + ((unsigned)node << 8) + gl16);
        float ep = arf[0] * bflo(mu.x) + arf[1] * bfhi(mu.x)
                 + arf[2] * bflo(mu.y) + arf[3] * bfhi(mu.y)
                 + arf[4] * bflo(mu.z) + arf[5] * bfhi(mu.z)
                 + arf[6] * bflo(mu.w) + arf[7] * bfhi(mu.w);
        er_h = ep + __shfl_xor(ep, 1);
    }

    float acc[8];
    #pragma unroll
    for (int k = 0; k < 8; ++k) acc[k] = 0.f;
    float s = 0.f;

    for (int j0 = 0; j0 < deg; j0 += 8) {
        uint4 rv[8];
        float wv8[8];
        #pragma unroll
        for (int q = 0; q < 8; ++q) {
            int j = j0 + q;
            bool act = j < deg;
            int2 p2 = snw[act ? beg + j : 0];
            wv8[q] = act ? __int_as_float(p2.y) : 0.f;
            unsigned ad = act ? (((unsigned)p2.x << 8) + gl16) : gl16;
            rv[q] = *(const uint4*)(fb + ad);
        }
        #pragma unroll
        for (int q = 0; q < 8; ++q) {
            float ep = alf[0] * bflo(rv[q].x) + alf[1] * bfhi(rv[q].x)
                     + alf[2] * bflo(rv[q].y) + alf[3] * bfhi(rv[q].y)
                     + alf[4] * bflo(rv[q].z) + alf[5] * bfhi(rv[q].z)
                     + alf[6] * bflo(rv[q].w) + alf[7] * bfhi(rv[q].w);
            float el_h = ep + __shfl_xor(ep, 1);
            float tt = el_h + er_h;
            tt = tt > 0.f ? tt : NEG_SLOPE * tt;
            float p = __expf(tt * wv8[q]);
            p = (j0 + q < deg) ? p : 0.f;
            s += p;
            acc[0] += p * bflo(rv[q].x); acc[1] += p * bfhi(rv[q].x);
            acc[2] += p * bflo(rv[q].y); acc[3] += p * bfhi(rv[q].y);
            acc[4] += p * bflo(rv[q].z); acc[5] += p * bfhi(rv[q].z);
            acc[6] += p * bflo(rv[q].w); acc[7] += p * bfhi(rv[q].w);
        }
    }

    if (valid) {
        float sinv = s > 0.f ? 1.f / s : 0.f;
        float o[8];
        #pragma unroll
        for (int k = 0; k < 8; ++k) o[k] = fmaxf(acc[k] * sinv, 0.f);
        uint4 pk;
        pk.x = f2bf(o[0]) | ((unsigned)f2bf(o[1]) << 16);
        pk.y = f2bf(o[2]) | ((unsigned)f2bf(o[3]) << 16);
        pk.z = f2bf(o[4]) | ((unsigned)f2bf(o[5]) << 16);
        pk.w = f2bf(o[6]) | ((unsigned)f2bf(o[7]) << 16);
        *(uint4*)((char*)out + ((size_t)node << 8) + gl16) = pk;
    }
}

extern "C" void kernel_launch(void* const* d_in, const int* in_sizes, int n_in,
                              void* d_out, int out_size, void* d_ws, size_t ws_size,
                              hipStream_t stream) {
    const float* features = (const float*)d_in[0];
    const int*   src      = (const int*)d_in[1];
    const int*   dst      = (const int*)d_in[2];
    const float* w        = (const float*)d_in[3];
    const float* W1       = (const float*)d_in[4];
    const float* al1      = (const float*)d_in[5];
    const float* ar1      = (const float*)d_in[6];
    const float* W2       = (const float*)d_in[7];
    const float* al2      = (const float*)d_in[8];
    const float* ar2      = (const float*)d_in[9];
    const float* Wm       = (const float*)d_in[10];
    const float* bm       = (const float*)d_in[11];
    float* out = (float*)d_out;

    const int N = in_sizes[0] / 128;   // 100000 < 2^17 (packing assumption)
    const int E = in_sizes[1];

    char* ws = (char*)d_ws;
    unsigned short* ftb = (unsigned short*)ws;            ws += (size_t)N * 128 * 2;
    unsigned short* x1b = (unsigned short*)ws;            ws += (size_t)N * 128 * 2;
    unsigned short* x2b = (unsigned short*)ws;            ws += (size_t)N * 128 * 2;
    unsigned short* Wt1 = (unsigned short*)ws;            ws += (size_t)128 * 128 * 2;
    unsigned short* Wt2 = (unsigned short*)ws;            ws += (size_t)128 * 128 * 2;
    unsigned short* Wtm = (unsigned short*)ws;            ws += (size_t)128 * 256 * 2;
    int* offs      = (int*)ws;                            ws += (size_t)(N + 4) * 4;
    int* bin_counts= (int*)ws;                            ws += 256 * 4;
    int* binoffs   = (int*)ws;                            ws += 260 * 4;
    int* gcur      = (int*)ws;                            ws += 256 * 4;
    int* dhist     = (int*)ws;                            ws += DMAX * 4;
    int* dcur      = (int*)ws;                            ws += DMAX * 4;
    int* perm      = (int*)ws;                            ws += (size_t)N * 4;
    int2* snw      = (int2*)ws;                           ws += (size_t)E * 8;
    int2* tmp      = (int2*)ws;                           ws += (size_t)E * 8;

    hipMemsetAsync(bin_counts, 0, 256 * sizeof(int), stream);
    hipMemsetAsync(dhist, 0, DMAX * sizeof(int), stream);

    const int nbins = (N + 511) >> BINSH;
    const int nblk_e = (E + EPB - 1) / EPB;
    const int nblk_n = (N + 255) / 256;

    binhist_k<<<nblk_e, 256, 0, stream>>>(dst, bin_counts, E, W1, W2, Wm, Wt1, Wt2, Wtm);
    scan256_k<<<1, 256, 0, stream>>>(bin_counts, binoffs, gcur, nbins);
    binify_k<<<nblk_e, 256, 0, stream>>>(src, dst, w, gcur, tmp, E);
    binfin_k<<<nbins, 256, 0, stream>>>(tmp, binoffs, offs, snw, dhist, N, E);
    degscan_k<<<1, 256, 0, stream>>>(dhist, dcur);
    degscat_k<<<nblk_n, 256, 0, stream>>>(offs, dcur, perm, N);

    int gemm_grid = (N + 127) / 128;
    int agg_grid = (N + 15) / 16;

    // ---- layer 1 ----
    gemm_mfma<128, true, false, true><<<gemm_grid, 256, 0, stream>>>(features, nullptr, Wt1, nullptr, ftb, N);
    agg_k<<<agg_grid, 256, 0, stream>>>((const __hip_bfloat16*)ftb, snw, offs, perm, al1, ar1, x1b, N);

    // ---- layer 2 ----
    gemm_mfma<128, false, false, true><<<gemm_grid, 256, 0, stream>>>(x1b, nullptr, Wt2, nullptr, ftb, N);
    agg_k<<<agg_grid, 256, 0, stream>>>((const __hip_bfloat16*)ftb, snw, offs, perm, al2, ar2, x2b, N);

    // ---- final: [x1|x2] @ Wm + bm (f32 out) ----
    gemm_mfma<256, false, true, false><<<gemm_grid, 256, 0, stream>>>(x1b, x2b, Wtm, bm, out, N);
}